// Round 2
// baseline (89.024 us; speedup 1.0000x reference)
//
#include <hip/hip_runtime.h>

#define NTOT 4096
#define FD 32
#define BATCH 4

typedef __attribute__((ext_vector_type(8))) _Float16 half8;
typedef __attribute__((ext_vector_type(4))) _Float16 half4;
typedef __attribute__((ext_vector_type(2))) _Float16 half2v;
typedef __attribute__((ext_vector_type(4))) float f32x4;

__device__ __forceinline__ float tanh_pos(float t) {
    // tanh(t) for t >= 0:  1 - 2/(1+e^{2t});  t=inf -> 1 correctly
    float u = __builtin_amdgcn_exp2f(t * 2.885390081777927f); // e^{2t}
    float r = __builtin_amdgcn_rcpf(u + 1.0f);
    return 1.0f - 2.0f * r;
}

__device__ __forceinline__ float eluf(float x) {
    return x > 0.0f ? x : (__builtin_amdgcn_exp2f(x * 1.4426950408889634f) - 1.0f);
}

// Convert X (f32, [B][NT][F]) -> Xh (f16 row-major) and Xht (f16 transposed [B][F][NT])
__global__ __launch_bounds__(256) void convert_x(const float* __restrict__ X,
                                                 _Float16* __restrict__ Xh,
                                                 _Float16* __restrict__ Xht) {
    __shared__ float lds[FD * 129];
    const int tid = threadIdx.x;
    const int b = blockIdx.x >> 5;          // 32 blocks per batch
    const int nbase = (blockIdx.x & 31) << 7;  // 128 rows per block
    const float* Xp = X + ((size_t)b * NTOT + nbase) * FD;
    _Float16* Xhp = Xh + ((size_t)b * NTOT + nbase) * FD;
#pragma unroll
    for (int k = 0; k < 16; ++k) {
        int e = tid + k * 256;
        int n = e >> 5, f = e & 31;
        float x = Xp[e];
        Xhp[e] = (_Float16)x;
        lds[f * 129 + n] = x;
    }
    __syncthreads();
    _Float16* Xtp = Xht + (size_t)b * FD * NTOT + nbase;
#pragma unroll
    for (int k = 0; k < 16; ++k) {
        int o = tid + k * 256;
        int f = o >> 7, nl = o & 127;
        Xtp[(size_t)f * NTOT + nl] = (_Float16)lds[f * 129 + nl];
    }
}

// One GCN layer:  out = elu( adj @ V @ W ),  adj = tanh(relu(X X^T) + I)
// Xh : f16 [B][NT][FD]  (Q and K source, always X)
// Vt : f16 [B][FD][NT]  (V^T: X^T for layer 0, H1^T for layer 1)
// LAYER==0: write outHt (f16 [B][FD][NT]); LAYER==1: write outF (f32 [B][NT][FD])
template <int LAYER>
__global__ __launch_bounds__(512) void gcn_layer_kernel(const _Float16* __restrict__ Xh,
                                                        const _Float16* __restrict__ Vt,
                                                        const float* __restrict__ Wg,
                                                        _Float16* __restrict__ outHt,
                                                        float* __restrict__ outF) {
    __shared__ float lds_part[8 * 32 * 32];  // per-wave partial O^T [w][f][r]
    __shared__ float lds_out[32 * 33];       // transpose staging (layer 0)

    const int tid = threadIdx.x;
    const int lane = tid & 63;
    const int wv = tid >> 6;                   // 8 waves
    const int b = blockIdx.x >> 7;             // 128 row-blocks per batch
    const int rowbase = (blockIdx.x & 127) << 5;  // 32 rows per block

    const int l15 = lane & 15;
    const int lg = lane >> 4;  // 0..3

    const _Float16* Xb = Xh + (size_t)b * NTOT * FD;
    // Q fragments (B-operand of 16x16x32: lane holds Q[l15][lg*8 + 0..7])
    const _Float16* qp = Xb + (size_t)(rowbase + l15) * FD + lg * 8;
    const half8 q1 = *(const half8*)qp;
    const half8 q2 = *(const half8*)(qp + 16 * FD);

    const int col0 = wv << 9;  // each wave owns 512 columns
    const _Float16* kp = Xb + (size_t)(col0 + l15) * FD + lg * 8;
    const _Float16* Vb = Vt + (size_t)b * FD * NTOT;
    const _Float16* vp0 = Vb + (size_t)l15 * NTOT + col0 + lg * 4;
    const _Float16* vp1 = vp0 + 16 * NTOT;

    f32x4 acc00 = {0.f, 0.f, 0.f, 0.f}, acc01 = {0.f, 0.f, 0.f, 0.f};
    f32x4 acc10 = {0.f, 0.f, 0.f, 0.f}, acc11 = {0.f, 0.f, 0.f, 0.f};
    const f32x4 zero = {0.f, 0.f, 0.f, 0.f};

    for (int it = 0; it < 32; ++it) {
        const int colbase = col0 + (it << 4);
        half8 kf = *(const half8*)kp;
        kp += 16 * FD;
        half4 v0 = *(const half4*)vp0;
        vp0 += 16;
        half4 v1 = *(const half4*)vp1;
        vp1 += 16;

        // S^T tiles: D[m][r], m=(lane>>4)*4+reg (col), r=lane&15 (row)
        f32x4 s1 = __builtin_amdgcn_mfma_f32_16x16x32_f16(kf, q1, zero, 0, 0, 0);
        f32x4 s2 = __builtin_amdgcn_mfma_f32_16x16x32_f16(kf, q2, zero, 0, 0, 0);

        float t1[4], t2[4];
#pragma unroll
        for (int e = 0; e < 4; ++e) {
            t1[e] = fmaxf(s1[e], 0.0f);
            t2[e] = fmaxf(s2[e], 0.0f);
        }
        if (colbase == rowbase) {  // diagonal hits rows rowbase..rowbase+15
#pragma unroll
            for (int e = 0; e < 4; ++e)
                if (lg * 4 + e == l15) t1[e] += 1.0f;
        }
        if (colbase == rowbase + 16) {  // diagonal hits rows rowbase+16..rowbase+31
#pragma unroll
            for (int e = 0; e < 4; ++e)
                if (lg * 4 + e == l15) t2[e] += 1.0f;
        }
#pragma unroll
        for (int e = 0; e < 4; ++e) {
            t1[e] = tanh_pos(t1[e]);
            t2[e] = tanh_pos(t2[e]);
        }

        half2v a0 = __builtin_bit_cast(half2v, __builtin_amdgcn_cvt_pkrtz(t1[0], t1[1]));
        half2v a1 = __builtin_bit_cast(half2v, __builtin_amdgcn_cvt_pkrtz(t1[2], t1[3]));
        half2v b0 = __builtin_bit_cast(half2v, __builtin_amdgcn_cvt_pkrtz(t2[0], t2[1]));
        half2v b1 = __builtin_bit_cast(half2v, __builtin_amdgcn_cvt_pkrtz(t2[2], t2[3]));
        half4 p1 = __builtin_shufflevector(a0, a1, 0, 1, 2, 3);
        half4 p2 = __builtin_shufflevector(b0, b1, 0, 1, 2, 3);

        // O^T += V^T_half * P^T   (D of QK == B-layout of 16x16x16 — direct chain)
        acc00 = __builtin_amdgcn_mfma_f32_16x16x16f16(v0, p1, acc00, 0, 0, 0);
        acc01 = __builtin_amdgcn_mfma_f32_16x16x16f16(v0, p2, acc01, 0, 0, 0);
        acc10 = __builtin_amdgcn_mfma_f32_16x16x16f16(v1, p1, acc10, 0, 0, 0);
        acc11 = __builtin_amdgcn_mfma_f32_16x16x16f16(v1, p2, acc11, 0, 0, 0);
    }

    // ---- store per-wave partial O^T [f=32][r=32] ----
#pragma unroll
    for (int e = 0; e < 4; ++e) {
        int f0 = lg * 4 + e;
        lds_part[(wv * 32 + f0) * 32 + l15] = acc00[e];
        lds_part[(wv * 32 + f0) * 32 + 16 + l15] = acc01[e];
        lds_part[(wv * 32 + 16 + f0) * 32 + l15] = acc10[e];
        lds_part[(wv * 32 + 16 + f0) * 32 + 16 + l15] = acc11[e];
    }
    __syncthreads();

    // ---- reduce the 8 wave partials into lds_part[0] ----
#pragma unroll
    for (int k = 0; k < 2; ++k) {
        int o = tid + k * 512;
        int f = o >> 5, r = o & 31;
        float s = 0.0f;
#pragma unroll
        for (int ww = 0; ww < 8; ++ww) s += lds_part[(ww * 32 + f) * 32 + r];
        lds_part[f * 32 + r] = s;  // each (f,r) owned by exactly one thread
    }
    __syncthreads();

    // ---- G = O @ W, elu, write ----
    const int r = tid >> 4;    // 0..31
    const int g0 = tid & 15;   // 0..15 (also handles g0+16)
    float a0 = 0.0f, a1 = 0.0f;
#pragma unroll
    for (int f = 0; f < FD; ++f) {
        float val = lds_part[f * 32 + r];
        a0 += val * Wg[f * FD + g0];
        a1 += val * Wg[f * FD + g0 + 16];
    }
    a0 = eluf(a0);
    a1 = eluf(a1);

    if (LAYER == 0) {
        lds_out[r * 33 + g0] = a0;
        lds_out[r * 33 + g0 + 16] = a1;
        __syncthreads();
        _Float16* dst = outHt + (size_t)b * FD * NTOT;
#pragma unroll
        for (int k = 0; k < 2; ++k) {
            int o = tid + k * 512;
            int gg = o >> 5, nl = o & 31;
            dst[(size_t)gg * NTOT + rowbase + nl] = (_Float16)lds_out[nl * 33 + gg];
        }
    } else {
        float* dst = outF + ((size_t)b * NTOT + rowbase + r) * FD;
        dst[g0] = a0;
        dst[g0 + 16] = a1;
    }
}

extern "C" void kernel_launch(void* const* d_in, const int* in_sizes, int n_in,
                              void* d_out, int out_size, void* d_ws, size_t ws_size,
                              hipStream_t stream) {
    const float* X = (const float*)d_in[0];  // [B][NT][FD] f32
    const float* W = (const float*)d_in[1];  // [2][FD][FD] f32
    float* out = (float*)d_out;              // [B][NT][FD] f32

    _Float16* Xh = (_Float16*)d_ws;                 // 524288 f16 = 1 MB
    _Float16* Xht = Xh + (size_t)BATCH * NTOT * FD; // 1 MB
    _Float16* H1t = Xht + (size_t)BATCH * NTOT * FD; // 1 MB

    convert_x<<<128, 256, 0, stream>>>(X, Xh, Xht);
    gcn_layer_kernel<0><<<512, 512, 0, stream>>>(Xh, Xht, W, H1t, nullptr);
    gcn_layer_kernel<1><<<512, 512, 0, stream>>>(Xh, H1t, W + FD * FD, nullptr, out);
}